// Round 6
// baseline (113.570 us; speedup 1.0000x reference)
//
#include <hip/hip_runtime.h>
#include <math.h>

// ---------------------------------------------------------------------------
// Difflogic network, collapsed form:
//   per neuron: out = c0 + c1*p + c2*q + c3*p*q,  p = A·x, q = B·x
//   A,B = softmax(sel), (c0..c3) = softmax(gate_logits) · gate-coef table
//
// R5 -> R6:
//  * net_kernel: x now staged through LDS with perfectly-coalesced float4
//    (16 lines/inst) instead of direct 144-B-stride dwordx4 (64 lines/inst,
//    ~4x the L1 transactions -- the R5 latency theory). Readback row stride
//    9 words (odd) -> 2 lanes/bank, free. Body unchanged from R5 (clean,
//    straight-line, cf[] via uniform constant-offset s_loads).
//  * coeff_kernel: 45 independent tasks (15 softmax-A, 15 softmax-B,
//    15 gate-folds) now one-per-lane instead of 3 serial per lane.
//
// ws layout (floats):
//   A1:   0 (72)   B1:  72 (72)   C1: 144 (32)
//   A2: 176 (32)   B2: 208 (32)   C2: 240 (16)
//   A3: 256 ( 8)   B3: 264 ( 8)   C3: 272 ( 8)
//   A4: 280 ( 2)   B4: 282 ( 2)   C4: 284 ( 4)   total 288 floats = 1152 B
// ---------------------------------------------------------------------------

#define THREADS 256
#define SPT 4                          // samples per thread
#define B_PER_BLOCK (THREADS * SPT)    // 1024 samples / block

template <int D>
__device__ __forceinline__ void softmax_row(const float* __restrict__ src,
                                            float* __restrict__ dst) {
    float e[D];
    float m = src[0];
    #pragma unroll
    for (int i = 1; i < D; ++i) m = fmaxf(m, src[i]);
    float s = 0.f;
    #pragma unroll
    for (int i = 0; i < D; ++i) { e[i] = __expf(src[i] - m); s += e[i]; }
    float inv = 1.f / s;
    #pragma unroll
    for (int i = 0; i < D; ++i) dst[i] = e[i] * inv;
}

__device__ __forceinline__ void gate_fold(const float* __restrict__ g,
                                          float* __restrict__ C) {
    const float k0[16]  = {0,0,0,0, 0,0,0,0, 1, 1, 1, 1, 1, 1, 1, 1};
    const float kp[16]  = {0,0,1,1, 0,0,1,1,-1,-1, 0, 0,-1,-1, 0, 0};
    const float kq[16]  = {0,0,0,0, 1,1,1,1,-1,-1,-1,-1, 0, 0, 0, 0};
    const float kpq[16] = {0,1,-1,0,-1,0,-2,-1, 1, 2, 0, 1, 0, 1,-1, 0};
    float w[16];
    float m = g[0];
    #pragma unroll
    for (int i = 1; i < 16; ++i) m = fmaxf(m, g[i]);
    float s = 0.f;
    #pragma unroll
    for (int i = 0; i < 16; ++i) { w[i] = __expf(g[i] - m); s += w[i]; }
    float inv = 1.f / s;
    float c0 = 0, c1 = 0, c2 = 0, c3 = 0;
    #pragma unroll
    for (int i = 0; i < 16; ++i) {
        float wi = w[i] * inv;
        c0 = fmaf(wi, k0[i], c0); c1 = fmaf(wi, kp[i], c1);
        c2 = fmaf(wi, kq[i], c2); c3 = fmaf(wi, kpq[i], c3);
    }
    C[0] = c0; C[1] = c1; C[2] = c2; C[3] = c3;
}

__global__ void coeff_kernel(const float* __restrict__ sa1, const float* __restrict__ sb1, const float* __restrict__ g1,
                             const float* __restrict__ sa2, const float* __restrict__ sb2, const float* __restrict__ g2,
                             const float* __restrict__ sa3, const float* __restrict__ sb3, const float* __restrict__ g3,
                             const float* __restrict__ sa4, const float* __restrict__ sb4, const float* __restrict__ g4,
                             float* __restrict__ cf) {
    const int t = threadIdx.x;
    if (t < 15) {                 // softmax of sel_a rows
        int r = t;
        if      (r < 8)  softmax_row<9>(sa1 + r * 9,        cf + r * 9);
        else if (r < 12) softmax_row<8>(sa2 + (r - 8) * 8,  cf + 176 + (r - 8) * 8);
        else if (r < 14) softmax_row<4>(sa3 + (r - 12) * 4, cf + 256 + (r - 12) * 4);
        else             softmax_row<2>(sa4,                cf + 280);
    } else if (t >= 16 && t < 31) {   // softmax of sel_b rows
        int r = t - 16;
        if      (r < 8)  softmax_row<9>(sb1 + r * 9,        cf + 72 + r * 9);
        else if (r < 12) softmax_row<8>(sb2 + (r - 8) * 8,  cf + 208 + (r - 8) * 8);
        else if (r < 14) softmax_row<4>(sb3 + (r - 12) * 4, cf + 264 + (r - 12) * 4);
        else             softmax_row<2>(sb4,                cf + 282);
    } else if (t >= 32 && t < 47) {   // gate-logit folds
        int r = t - 32;
        if      (r < 8)  gate_fold(g1 + r * 16,        cf + 144 + r * 4);
        else if (r < 12) gate_fold(g2 + (r - 8) * 16,  cf + 240 + (r - 8) * 4);
        else if (r < 14) gate_fold(g3 + (r - 12) * 16, cf + 272 + (r - 12) * 4);
        else             gate_fold(g4,                 cf + 284);
    }
}

__global__ __launch_bounds__(THREADS, 3) void net_kernel(
        const float* __restrict__ x, const float* __restrict__ cf,
        float* __restrict__ out, int nB) {
    __shared__ float sx[B_PER_BLOCK * 9];          // 36 KB
    const int t = threadIdx.x;
    const int blockBase = blockIdx.x * B_PER_BLOCK;
    const int total  = nB * 9;
    const int f4base = blockBase * 9 / 4;          // exact: 2304 float4 / block

    // ---- stage 2304 float4 coalesced (16 lines per instruction) ----
    const float4* __restrict__ x4 = (const float4*)x;
    float4* sx4 = (float4*)sx;
    #pragma unroll
    for (int k = 0; k < 9; ++k) {
        int idx = t + k * THREADS;                 // [0, 2304)
        int fi  = f4base + idx;
        int e   = fi * 4;
        if (e + 3 < total) {
            sx4[idx] = x4[fi];
        } else {
            float4 vv = {0.f, 0.f, 0.f, 0.f};
            if (e     < total) vv.x = x[e];
            if (e + 1 < total) vv.y = x[e + 1];
            if (e + 2 < total) vv.z = x[e + 2];
            sx4[idx] = vv;
        }
    }
    __syncthreads();

    // ---- read back: row stride 9 words (odd) -> 2-way bank alias, free ----
    float v[SPT][9];
    #pragma unroll
    for (int s = 0; s < SPT; ++s) {
        const int r = s * THREADS + t;
        #pragma unroll
        for (int i = 0; i < 9; ++i) v[s][i] = sx[r * 9 + i];
    }

    // ---- Layer 1: 9 -> 8. cf[] = uniform pointer + constant offsets
    //      -> scalar loads; SGPR operands feed v_fma directly. ----
    float h1[SPT][8];
    #pragma unroll
    for (int j = 0; j < 8; ++j) {
        #pragma unroll
        for (int s = 0; s < SPT; ++s) {
            float p = 0.f, q = 0.f;
            #pragma unroll
            for (int i = 0; i < 9; ++i) {
                p = fmaf(v[s][i], cf[     j * 9 + i], p);
                q = fmaf(v[s][i], cf[72 + j * 9 + i], q);
            }
            h1[s][j] = fmaf(cf[144 + j*4 + 3], p * q,
                       fmaf(cf[144 + j*4 + 2], q,
                       fmaf(cf[144 + j*4 + 1], p, cf[144 + j*4 + 0])));
        }
    }
    // ---- Layer 2: 8 -> 4 ----
    float h2[SPT][4];
    #pragma unroll
    for (int j = 0; j < 4; ++j) {
        #pragma unroll
        for (int s = 0; s < SPT; ++s) {
            float p = 0.f, q = 0.f;
            #pragma unroll
            for (int i = 0; i < 8; ++i) {
                p = fmaf(h1[s][i], cf[176 + j * 8 + i], p);
                q = fmaf(h1[s][i], cf[208 + j * 8 + i], q);
            }
            h2[s][j] = fmaf(cf[240 + j*4 + 3], p * q,
                       fmaf(cf[240 + j*4 + 2], q,
                       fmaf(cf[240 + j*4 + 1], p, cf[240 + j*4 + 0])));
        }
    }
    // ---- Layer 3: 4 -> 2 ----
    float h3[SPT][2];
    #pragma unroll
    for (int j = 0; j < 2; ++j) {
        #pragma unroll
        for (int s = 0; s < SPT; ++s) {
            float p = 0.f, q = 0.f;
            #pragma unroll
            for (int i = 0; i < 4; ++i) {
                p = fmaf(h2[s][i], cf[256 + j * 4 + i], p);
                q = fmaf(h2[s][i], cf[264 + j * 4 + i], q);
            }
            h3[s][j] = fmaf(cf[272 + j*4 + 3], p * q,
                       fmaf(cf[272 + j*4 + 2], q,
                       fmaf(cf[272 + j*4 + 1], p, cf[272 + j*4 + 0])));
        }
    }
    // ---- Layer 4: 2 -> 1, one float4 store per thread ----
    float o[SPT];
    #pragma unroll
    for (int s = 0; s < SPT; ++s) {
        float p = fmaf(h3[s][0], cf[280], h3[s][1] * cf[281]);
        float q = fmaf(h3[s][0], cf[282], h3[s][1] * cf[283]);
        o[s] = fmaf(cf[287], p * q,
               fmaf(cf[286], q,
               fmaf(cf[285], p, cf[284])));
    }
    const int b0 = blockBase + t * SPT;            // NOTE: store mapping below
    // Store: thread t wrote samples {blockBase + s*256 + t}, which are NOT
    // consecutive -> scatter dwords would be uncoalesced. Instead round-trip
    // the 4 outputs through the (now dead) sx buffer to regroup, then do one
    // coalesced float4 store per thread.
    __syncthreads();
    #pragma unroll
    for (int s = 0; s < SPT; ++s) sx[s * THREADS + t] = o[s];
    __syncthreads();
    if (b0 + SPT <= nB) {
        float4* __restrict__ out4 = (float4*)out;
        const float4* __restrict__ sxo = (const float4*)sx;
        out4[blockBase / SPT + t] = sxo[t];        // sx[t*4 .. t*4+3]
    } else {
        #pragma unroll
        for (int s = 0; s < SPT; ++s)
            if (b0 + s < nB) out[b0 + s] = sx[t * SPT + s];
    }
}

extern "C" void kernel_launch(void* const* d_in, const int* in_sizes, int n_in,
                              void* d_out, int out_size, void* d_ws, size_t ws_size,
                              hipStream_t stream) {
    const float* x   = (const float*)d_in[0];
    const float* sa1 = (const float*)d_in[1];
    const float* sb1 = (const float*)d_in[2];
    const float* g1  = (const float*)d_in[3];
    const float* sa2 = (const float*)d_in[4];
    const float* sb2 = (const float*)d_in[5];
    const float* g2  = (const float*)d_in[6];
    const float* sa3 = (const float*)d_in[7];
    const float* sb3 = (const float*)d_in[8];
    const float* g3  = (const float*)d_in[9];
    const float* sa4 = (const float*)d_in[10];
    const float* sb4 = (const float*)d_in[11];
    const float* g4  = (const float*)d_in[12];
    float* cf = (float*)d_ws;                 // 288 floats of scratch
    const int nB = in_sizes[0] / 9;

    coeff_kernel<<<1, 64, 0, stream>>>(sa1, sb1, g1, sa2, sb2, g2,
                                       sa3, sb3, g3, sa4, sb4, g4, cf);
    const int grid = (nB + B_PER_BLOCK - 1) / B_PER_BLOCK;
    net_kernel<<<grid, THREADS, 0, stream>>>(x, cf, (float*)d_out, nB);
}